// Round 1
// baseline (356.909 us; speedup 1.0000x reference)
//
#include <hip/hip_runtime.h>
#include <cstdint>
#include <cstddef>

#define B_ 16
#define N_ 2048
#define L_ 12
#define C_ 32
#define KTOP 1638
#define SCALE 0.17677669529663687f   // 1/sqrt(32)

// Kernel 1: xsumT[b][c][n] = sum_l x[b][n][l][c]   (B,C,N layout, 4 MB in d_ws)
__global__ __launch_bounds__(256) void xsum_kernel(const float* __restrict__ x,
                                                   float* __restrict__ xsumT) {
  const int b = blockIdx.y;
  const int n0 = blockIdx.x * 64;
  __shared__ float tile[64][33];  // +1 pad: conflict-free transpose
  const int c = threadIdx.x & 31;
  const int nr = threadIdx.x >> 5;  // 0..7
#pragma unroll
  for (int i = 0; i < 8; ++i) {
    const int n = n0 + i * 8 + nr;
    const float* px = x + ((size_t)(b * N_ + n) * L_) * C_ + c;
    float s = 0.f;
#pragma unroll
    for (int l = 0; l < L_; ++l) s += px[l * C_];
    tile[i * 8 + nr][c] = s;
  }
  __syncthreads();
  const int n2 = threadIdx.x & 63;
  const int c2b = threadIdx.x >> 6;  // 0..3
#pragma unroll
  for (int i = 0; i < 8; ++i) {
    const int c2 = c2b + i * 4;
    xsumT[((size_t)b * C_ + c2) * N_ + n0 + n2] = tile[n2][c2];
  }
}

// Kernel 2: one block = 8 rows of one batch. Fused e1/e2 GEMV + softmaxes +
// linear combo + top-k threshold mask + final softmax.
__global__ __launch_bounds__(256, 2) void adj_kernel(
    const float* __restrict__ xsumT, const float* __restrict__ mem,
    const float* __restrict__ fc_w, const float* __restrict__ fc_b,
    float* __restrict__ out) {
  __shared__ float adjbuf[8][2048];   // 64 KB
  __shared__ float xrow[8][32];
  __shared__ float red[4][16];

  const int tid = threadIdx.x;
  const int b = blockIdx.y;
  const int n0 = blockIdx.x * 8;

  {
    const int r = tid >> 5, c = tid & 31;
    xrow[r][c] = xsumT[((size_t)b * C_ + c) * N_ + n0 + r];
  }
  __syncthreads();

  // ---- Phase A: dot products. Thread owns columns m = tid*8 .. tid*8+7 ----
  float acc1[8][8], acc2[8][8];
#pragma unroll
  for (int r = 0; r < 8; ++r)
#pragma unroll
    for (int j = 0; j < 8; ++j) { acc1[r][j] = 0.f; acc2[r][j] = 0.f; }

  const float* mp = mem + tid * 8;
  const float* xp = xsumT + (size_t)b * C_ * N_ + tid * 8;

#pragma unroll 2
  for (int c = 0; c < C_; ++c) {
    float m8[8], x8[8];
    float4 t;
    t = *(const float4*)(mp + (size_t)c * N_);     m8[0]=t.x; m8[1]=t.y; m8[2]=t.z; m8[3]=t.w;
    t = *(const float4*)(mp + (size_t)c * N_ + 4); m8[4]=t.x; m8[5]=t.y; m8[6]=t.z; m8[7]=t.w;
    t = *(const float4*)(xp + (size_t)c * N_);     x8[0]=t.x; x8[1]=t.y; x8[2]=t.z; x8[3]=t.w;
    t = *(const float4*)(xp + (size_t)c * N_ + 4); x8[4]=t.x; x8[5]=t.y; x8[6]=t.z; x8[7]=t.w;
#pragma unroll
    for (int r = 0; r < 8; ++r) {
      const float xv = xrow[r][c];
#pragma unroll
      for (int j = 0; j < 8; ++j) {
        acc1[r][j] = fmaf(xv, m8[j], acc1[r][j]);
        acc2[r][j] = fmaf(xv, x8[j], acc2[r][j]);
      }
    }
  }

  // relu(e*scale)
#pragma unroll
  for (int r = 0; r < 8; ++r)
#pragma unroll
    for (int j = 0; j < 8; ++j) {
      acc1[r][j] = fmaxf(acc1[r][j] * SCALE, 0.f);
      acc2[r][j] = fmaxf(acc2[r][j] * SCALE, 0.f);
    }

  const int wid = tid >> 6, lane = tid & 63;

  // ---- block max over 16 channels (M1[0..7], M2[0..7]) ----
  float mx[16];
#pragma unroll
  for (int r = 0; r < 8; ++r) {
    float a = acc1[r][0], b2 = acc2[r][0];
#pragma unroll
    for (int j = 1; j < 8; ++j) { a = fmaxf(a, acc1[r][j]); b2 = fmaxf(b2, acc2[r][j]); }
    mx[r] = a; mx[8 + r] = b2;
  }
#pragma unroll
  for (int d = 1; d < 64; d <<= 1)
#pragma unroll
    for (int ch = 0; ch < 16; ++ch) mx[ch] = fmaxf(mx[ch], __shfl_xor(mx[ch], d));
  if (lane == 0) {
#pragma unroll
    for (int ch = 0; ch < 16; ++ch) red[wid][ch] = mx[ch];
  }
  __syncthreads();
#pragma unroll
  for (int ch = 0; ch < 16; ++ch) {
    float v = red[0][ch];
#pragma unroll
    for (int w = 1; w < 4; ++w) v = fmaxf(v, red[w][ch]);
    mx[ch] = v;
  }
  __syncthreads();

  // ---- exp + block sum (D1, D2) ----
  float sm[16];
#pragma unroll
  for (int r = 0; r < 8; ++r) {
    float s1 = 0.f, s2 = 0.f;
#pragma unroll
    for (int j = 0; j < 8; ++j) {
      acc1[r][j] = __expf(acc1[r][j] - mx[r]);
      acc2[r][j] = __expf(acc2[r][j] - mx[8 + r]);
      s1 += acc1[r][j]; s2 += acc2[r][j];
    }
    sm[r] = s1; sm[8 + r] = s2;
  }
#pragma unroll
  for (int d = 1; d < 64; d <<= 1)
#pragma unroll
    for (int ch = 0; ch < 16; ++ch) sm[ch] += __shfl_xor(sm[ch], d);
  if (lane == 0) {
#pragma unroll
    for (int ch = 0; ch < 16; ++ch) red[wid][ch] = sm[ch];
  }
  __syncthreads();
#pragma unroll
  for (int ch = 0; ch < 16; ++ch) {
    float v = 0.f;
#pragma unroll
    for (int w = 0; w < 4; ++w) v += red[w][ch];
    sm[ch] = v;
  }

  // ---- adj = w0*a1 + w1*a2 + b, stage to LDS ----
  const float w0 = fc_w[0], w1 = fc_w[1], bb = fc_b[0];
#pragma unroll
  for (int r = 0; r < 8; ++r) {
    const float i1 = w0 / sm[r];
    const float i2 = w1 / sm[8 + r];
#pragma unroll
    for (int j = 0; j < 8; ++j) {
      adjbuf[r][tid * 8 + j] = fmaf(acc1[r][j], i1, fmaf(acc2[r][j], i2, bb));
    }
  }
  __syncthreads();

  // ---- Phase B: wave w owns rows 2w, 2w+1. Threshold search + final softmax ----
#pragma unroll 1
  for (int half = 0; half < 2; ++half) {
    const int r = wid * 2 + half;
    float a[32];
    unsigned u[32];
#pragma unroll
    for (int k = 0; k < 8; ++k) {
      float4 v = *(const float4*)&adjbuf[r][lane * 4 + k * 256];
      a[k * 4 + 0] = v.x; a[k * 4 + 1] = v.y; a[k * 4 + 2] = v.z; a[k * 4 + 3] = v.w;
    }
#pragma unroll
    for (int i = 0; i < 32; ++i) {
      const int bi = __float_as_int(a[i]);
      u[i] = (unsigned)bi ^ (unsigned)((bi >> 31) | 0x80000000);
    }
    unsigned mn = u[0], mxu = u[0];
#pragma unroll
    for (int i = 1; i < 32; ++i) { mn = min(mn, u[i]); mxu = max(mxu, u[i]); }
#pragma unroll
    for (int d = 1; d < 64; d <<= 1) {
      mn  = min(mn,  (unsigned)__shfl_xor((int)mn,  d));
      mxu = max(mxu, (unsigned)__shfl_xor((int)mxu, d));
    }
    unsigned lo = mn, hi = mxu;
    for (int it = 0; it < 24; ++it) {
      if (lo >= hi) break;
      const unsigned mid = (unsigned)(((unsigned long long)lo + hi + 1ull) >> 1);
      int cnt = 0;
#pragma unroll
      for (int i = 0; i < 32; ++i) cnt += (int)__popcll(__ballot(u[i] >= mid));
      if (cnt >= KTOP) lo = mid; else hi = mid - 1;
    }
    // mask (zero dropped entries), final softmax
    float m3 = 0.f;   // masked zeros participate; softmax shift-invariant anyway
#pragma unroll
    for (int i = 0; i < 32; ++i) {
      const float l = (u[i] >= lo) ? a[i] : 0.f;
      a[i] = l;
      m3 = fmaxf(m3, l);
    }
#pragma unroll
    for (int d = 1; d < 64; d <<= 1) m3 = fmaxf(m3, __shfl_xor(m3, d));
    float s = 0.f;
#pragma unroll
    for (int i = 0; i < 32; ++i) { a[i] = __expf(a[i] - m3); s += a[i]; }
#pragma unroll
    for (int d = 1; d < 64; d <<= 1) s += __shfl_xor(s, d);
    const float inv = 1.f / s;
    float* op = out + ((size_t)b * N_ + n0 + r) * N_;
#pragma unroll
    for (int k = 0; k < 8; ++k) {
      float4 o;
      o.x = a[k * 4 + 0] * inv; o.y = a[k * 4 + 1] * inv;
      o.z = a[k * 4 + 2] * inv; o.w = a[k * 4 + 3] * inv;
      *(float4*)(op + lane * 4 + k * 256) = o;
    }
  }
}

extern "C" void kernel_launch(void* const* d_in, const int* in_sizes, int n_in,
                              void* d_out, int out_size, void* d_ws, size_t ws_size,
                              hipStream_t stream) {
  const float* x   = (const float*)d_in[0];
  const float* mem = (const float*)d_in[1];
  const float* fcw = (const float*)d_in[2];
  const float* fcb = (const float*)d_in[3];
  float* out = (float*)d_out;
  float* xsumT = (float*)d_ws;  // B_*C_*N_ floats = 4 MB

  dim3 g1(N_ / 64, B_);
  xsum_kernel<<<g1, 256, 0, stream>>>(x, xsumT);
  dim3 g2(N_ / 8, B_);
  adj_kernel<<<g2, 256, 0, stream>>>(xsumT, mem, fcw, fcb, out);
}

// Round 2
// 325.055 us; speedup vs baseline: 1.0980x; 1.0980x over previous
//
#include <hip/hip_runtime.h>
#include <cstdint>
#include <cstddef>

#define B_ 16
#define N_ 2048
#define L_ 12
#define C_ 32
#define KTOP 1638
#define SCALE 0.17677669529663687f   // 1/sqrt(32)

// Kernel 1: xsumT[b][c][n] = sum_l x[b][n][l][c]   (B,C,N layout, 4 MB in d_ws)
__global__ __launch_bounds__(256) void xsum_kernel(const float* __restrict__ x,
                                                   float* __restrict__ xsumT) {
  const int b = blockIdx.y;
  const int n0 = blockIdx.x * 64;
  __shared__ float tile[64][33];  // +1 pad: conflict-free transpose
  const int c = threadIdx.x & 31;
  const int nr = threadIdx.x >> 5;  // 0..7
#pragma unroll
  for (int i = 0; i < 8; ++i) {
    const int n = n0 + i * 8 + nr;
    const float* px = x + ((size_t)(b * N_ + n) * L_) * C_ + c;
    float s = 0.f;
#pragma unroll
    for (int l = 0; l < L_; ++l) s += px[l * C_];
    tile[i * 8 + nr][c] = s;
  }
  __syncthreads();
  const int n2 = threadIdx.x & 63;
  const int c2b = threadIdx.x >> 6;  // 0..3
#pragma unroll
  for (int i = 0; i < 8; ++i) {
    const int c2 = c2b + i * 4;
    xsumT[((size_t)b * C_ + c2) * N_ + n0 + n2] = tile[n2][c2];
  }
}

// Kernel 2: one block = 8 rows of one batch, 512 threads (8 waves).
// Thread owns 4 contiguous columns -> acc regs = 8 rows * 4 cols * 2 = 64.
__global__ __launch_bounds__(512, 4) void adj_kernel(
    const float* __restrict__ xsumT, const float* __restrict__ mem,
    const float* __restrict__ fc_w, const float* __restrict__ fc_b,
    float* __restrict__ out) {
  __shared__ float adjbuf[8][2048];   // 64 KB
  __shared__ float xrow[8][32];
  __shared__ float red[8][16];

  const int tid = threadIdx.x;
  const int wid = tid >> 6, lane = tid & 63;
  const int b = blockIdx.y;
  const int n0 = blockIdx.x * 8;

  if (tid < 256) {
    const int r = tid >> 5, c = tid & 31;
    xrow[r][c] = xsumT[((size_t)b * C_ + c) * N_ + n0 + r];
  }
  __syncthreads();

  // ---- Phase A: dot products. Thread owns columns m = tid*4 .. tid*4+3 ----
  float acc1[8][4], acc2[8][4];
#pragma unroll
  for (int r = 0; r < 8; ++r)
#pragma unroll
    for (int j = 0; j < 4; ++j) { acc1[r][j] = 0.f; acc2[r][j] = 0.f; }

  const float* mp = mem + tid * 4;
  const float* xp = xsumT + (size_t)b * C_ * N_ + tid * 4;

#pragma unroll 4
  for (int c = 0; c < C_; ++c) {
    const float4 mt = *(const float4*)(mp + (size_t)c * N_);
    const float4 xt = *(const float4*)(xp + (size_t)c * N_);
    const float m4[4] = {mt.x, mt.y, mt.z, mt.w};
    const float x4[4] = {xt.x, xt.y, xt.z, xt.w};
#pragma unroll
    for (int r = 0; r < 8; ++r) {
      const float xv = xrow[r][c];
#pragma unroll
      for (int j = 0; j < 4; ++j) {
        acc1[r][j] = fmaf(xv, m4[j], acc1[r][j]);
        acc2[r][j] = fmaf(xv, x4[j], acc2[r][j]);
      }
    }
  }

  // relu(e*scale)
#pragma unroll
  for (int r = 0; r < 8; ++r)
#pragma unroll
    for (int j = 0; j < 4; ++j) {
      acc1[r][j] = fmaxf(acc1[r][j] * SCALE, 0.f);
      acc2[r][j] = fmaxf(acc2[r][j] * SCALE, 0.f);
    }

  // ---- block max over 16 channels (rows 0..7 for e1, 8..15 for e2) ----
  float st[16];
#pragma unroll
  for (int r = 0; r < 8; ++r) {
    float a = acc1[r][0], b2 = acc2[r][0];
#pragma unroll
    for (int j = 1; j < 4; ++j) { a = fmaxf(a, acc1[r][j]); b2 = fmaxf(b2, acc2[r][j]); }
    st[r] = a; st[8 + r] = b2;
  }
#pragma unroll
  for (int d = 1; d < 64; d <<= 1)
#pragma unroll
    for (int ch = 0; ch < 16; ++ch) st[ch] = fmaxf(st[ch], __shfl_xor(st[ch], d));
  if (lane == 0) {
#pragma unroll
    for (int ch = 0; ch < 16; ++ch) red[wid][ch] = st[ch];
  }
  __syncthreads();
  float mx[16];
#pragma unroll
  for (int ch = 0; ch < 16; ++ch) {
    float v = red[0][ch];
#pragma unroll
    for (int w = 1; w < 8; ++w) v = fmaxf(v, red[w][ch]);
    mx[ch] = v;
  }
  __syncthreads();  // red about to be reused

  // ---- exp + block sum ----
#pragma unroll
  for (int r = 0; r < 8; ++r) {
    float s1 = 0.f, s2 = 0.f;
#pragma unroll
    for (int j = 0; j < 4; ++j) {
      acc1[r][j] = __expf(acc1[r][j] - mx[r]);
      acc2[r][j] = __expf(acc2[r][j] - mx[8 + r]);
      s1 += acc1[r][j]; s2 += acc2[r][j];
    }
    st[r] = s1; st[8 + r] = s2;
  }
#pragma unroll
  for (int d = 1; d < 64; d <<= 1)
#pragma unroll
    for (int ch = 0; ch < 16; ++ch) st[ch] += __shfl_xor(st[ch], d);
  if (lane == 0) {
#pragma unroll
    for (int ch = 0; ch < 16; ++ch) red[wid][ch] = st[ch];
  }
  __syncthreads();
  float sm[16];
#pragma unroll
  for (int ch = 0; ch < 16; ++ch) {
    float v = 0.f;
#pragma unroll
    for (int w = 0; w < 8; ++w) v += red[w][ch];
    sm[ch] = v;
  }

  // ---- adj = w0*a1 + w1*a2 + b, stage to LDS ----
  const float w0 = fc_w[0], w1 = fc_w[1], bb = fc_b[0];
#pragma unroll
  for (int r = 0; r < 8; ++r) {
    const float i1 = w0 / sm[r];
    const float i2 = w1 / sm[8 + r];
#pragma unroll
    for (int j = 0; j < 4; ++j) {
      adjbuf[r][tid * 4 + j] = fmaf(acc1[r][j], i1, fmaf(acc2[r][j], i2, bb));
    }
  }
  __syncthreads();

  // ---- Phase B: wave wid owns row wid. Threshold search + final softmax ----
  {
    const int r = wid;
    float a[32];
    unsigned u[32];
#pragma unroll
    for (int i = 0; i < 32; ++i) a[i] = adjbuf[r][lane + (i << 6)];  // stride-64: conflict-free
#pragma unroll
    for (int i = 0; i < 32; ++i) {
      const int bi = __float_as_int(a[i]);
      u[i] = (unsigned)bi ^ (unsigned)((bi >> 31) | 0x80000000);
    }
    unsigned mn = u[0], mxu = u[0];
#pragma unroll
    for (int i = 1; i < 32; ++i) { mn = min(mn, u[i]); mxu = max(mxu, u[i]); }
#pragma unroll
    for (int d = 1; d < 64; d <<= 1) {
      mn  = min(mn,  (unsigned)__shfl_xor((int)mn,  d));
      mxu = max(mxu, (unsigned)__shfl_xor((int)mxu, d));
    }
    unsigned lo = mn, hi = mxu;
    for (int it = 0; it < 24; ++it) {
      if (lo >= hi) break;
      const unsigned mid = (unsigned)(((unsigned long long)lo + hi + 1ull) >> 1);
      int cnt = 0;
#pragma unroll
      for (int i = 0; i < 32; ++i) cnt += (int)__popcll(__ballot(u[i] >= mid));
      if (cnt >= KTOP) lo = mid; else hi = mid - 1;
    }
    // mask (zero dropped entries), final softmax
    float m3 = 0.f;
#pragma unroll
    for (int i = 0; i < 32; ++i) {
      const float l = (u[i] >= lo) ? a[i] : 0.f;
      a[i] = l;
      m3 = fmaxf(m3, l);
    }
#pragma unroll
    for (int d = 1; d < 64; d <<= 1) m3 = fmaxf(m3, __shfl_xor(m3, d));
    float s = 0.f;
#pragma unroll
    for (int i = 0; i < 32; ++i) { a[i] = __expf(a[i] - m3); s += a[i]; }
#pragma unroll
    for (int d = 1; d < 64; d <<= 1) s += __shfl_xor(s, d);
    const float inv = 1.f / s;
    float* op = out + ((size_t)b * N_ + n0 + r) * N_;
#pragma unroll
    for (int i = 0; i < 32; ++i) op[lane + (i << 6)] = a[i] * inv;
  }
}

extern "C" void kernel_launch(void* const* d_in, const int* in_sizes, int n_in,
                              void* d_out, int out_size, void* d_ws, size_t ws_size,
                              hipStream_t stream) {
  const float* x   = (const float*)d_in[0];
  const float* mem = (const float*)d_in[1];
  const float* fcw = (const float*)d_in[2];
  const float* fcb = (const float*)d_in[3];
  float* out = (float*)d_out;
  float* xsumT = (float*)d_ws;  // B_*C_*N_ floats = 4 MB

  dim3 g1(N_ / 64, B_);
  xsum_kernel<<<g1, 256, 0, stream>>>(x, xsumT);
  dim3 g2(N_ / 8, B_);
  adj_kernel<<<g2, 512, 0, stream>>>(xsumT, mem, fcw, fcb, out);
}